// Round 1
// 406.003 us; speedup vs baseline: 1.0102x; 1.0102x over previous
//
#include <hip/hip_runtime.h>
#include <cstdint>
#include <cstddef>

typedef unsigned short u16;
typedef short v8s __attribute__((ext_vector_type(8)));
typedef float v4f __attribute__((ext_vector_type(4)));

constexpr int SEQ = 4096;
constexpr int FEAT = 2048;
constexpr int F3 = 6144;

// ---------- helpers ----------

__device__ __forceinline__ u16 f2bf(float f) {
  union { float f; uint32_t u; } v; v.f = f;
  uint32_t r = v.u + 0x7FFFu + ((v.u >> 16) & 1u);  // round-to-nearest-even
  return (u16)(r >> 16);
}

__device__ __forceinline__ float bf2f(u16 s) {
  union { uint32_t u; float f; } v; v.u = ((uint32_t)s) << 16;
  return v.f;
}

// async global->LDS, 16B per lane; lds dest is wave-uniform base (HW: base+lane*16)
__device__ __forceinline__ void gld_lds16(const u16* g, u16* l) {
  __builtin_amdgcn_global_load_lds(
      (const __attribute__((address_space(1))) void*)g,
      (__attribute__((address_space(3))) void*)l, 16, 0, 0);
}

// ---------- conversion / transpose ----------

__global__ void cvt_f32_bf16(const float* __restrict__ in, u16* __restrict__ out, int n8) {
  int i = blockIdx.x * 256 + threadIdx.x;
  if (i >= n8) return;
  const float4* p = (const float4*)in + (size_t)i * 2;
  float4 a = p[0], b = p[1];
  union { u16 s[8]; uint4 v; } u;
  u.s[0] = f2bf(a.x); u.s[1] = f2bf(a.y); u.s[2] = f2bf(a.z); u.s[3] = f2bf(a.w);
  u.s[4] = f2bf(b.x); u.s[5] = f2bf(b.y); u.s[6] = f2bf(b.z); u.s[7] = f2bf(b.w);
  *(uint4*)(out + (size_t)i * 8) = u.v;
}

__global__ void transp_f2b(const float* __restrict__ in, int ldin,
                           u16* __restrict__ out, int ldout) {
  __shared__ float tile[32][33];
  int c0 = blockIdx.x * 32, r0 = blockIdx.y * 32;
  int tx = threadIdx.x, ty = threadIdx.y;
#pragma unroll
  for (int p = 0; p < 4; ++p)
    tile[ty + 8 * p][tx] = in[(size_t)(r0 + ty + 8 * p) * ldin + c0 + tx];
  __syncthreads();
#pragma unroll
  for (int p = 0; p < 4; ++p)
    out[(size_t)(c0 + ty + 8 * p) * ldout + r0 + tx] = f2bf(tile[tx][ty + 8 * p]);
}

__global__ void transp_b2b(const u16* __restrict__ in, int ldin,
                           u16* __restrict__ out, int ldout) {
  __shared__ u16 tile[32][33];
  int c0 = blockIdx.x * 32, r0 = blockIdx.y * 32;
  int tx = threadIdx.x, ty = threadIdx.y;
#pragma unroll
  for (int p = 0; p < 4; ++p)
    tile[ty + 8 * p][tx] = in[(size_t)(r0 + ty + 8 * p) * ldin + c0 + tx];
  __syncthreads();
#pragma unroll
  for (int p = 0; p < 4; ++p)
    out[(size_t)(c0 + ty + 8 * p) * ldout + r0 + tx] = tile[tx][ty + 8 * p];
}

// ---------- legacy 128x128 GEMM (kept for causal att@v, MODE 2) ----------
// C[M,N] = A[M,K] * B[N,K]^T (bf16, k contiguous). BM=BN=128, BK=64 as
// 2x(128x32) sub-tiles. 256 thr = 4 waves, 2x2 of 64x64, 16x16x32 MFMA.
// LDS chunk swizzle (verified conflict-free): chunk (row,col8) at
// col8' = (col8 + (row>>1))&3; staging inverts.
// MODE 2: causal split-K z=2 (half=(bi+1)*64), atomicAdd fp32.
template<int OUTBF, int ADDB, int MODE>
__global__ __launch_bounds__(256) void gemm_bt(
    const u16* __restrict__ A, int lda,
    const u16* __restrict__ B, int ldb,
    void* __restrict__ Cv, int ldc,
    int K, const float* __restrict__ bias, float scale) {
  int bi, bj, ks, ke;
  if (MODE == 2) {
    bi = blockIdx.y; bj = blockIdx.x;
    const int half = (bi + 1) * 64;          // kend/2, multiple of 64
    ks = blockIdx.z * half; ke = ks + half;
  } else {
    bi = blockIdx.y; bj = blockIdx.x;
    ks = 0; ke = K;
  }
  const int i0 = bi * 128, j0 = bj * 128;

  __shared__ u16 As[128 * 64];   // sub-tile s at element offset s*4096
  __shared__ u16 Bs[128 * 64];

  const int t = threadIdx.x;
  const int w = t >> 6, l = t & 63;
  const int wr = w >> 1, wc = w & 1;
  const int lm = l & 15, lq = l >> 4;
  const int lqs = ((lq + (lm >> 1)) & 3) * 8;  // swizzled col8' element offset

  v4f acc[4][4];
#pragma unroll
  for (int a = 0; a < 4; ++a)
#pragma unroll
    for (int b = 0; b < 4; ++b)
      acc[a][b] = v4f{0.f, 0.f, 0.f, 0.f};

  const int c1 = t + 256;
  const int r0c = t >> 2, o0 = ((((t & 3) - ((t >> 3) & 3)) & 3)) * 8;
  const int r1c = c1 >> 2, o1 = ((((c1 & 3) - ((c1 >> 3) & 3)) & 3)) * 8;
  const u16* Ag0 = A + (size_t)(i0 + r0c) * lda + o0;
  const u16* Ag1 = A + (size_t)(i0 + r1c) * lda + o1;
  const u16* Bg0 = B + (size_t)(j0 + r0c) * ldb + o0;
  const u16* Bg1 = B + (size_t)(j0 + r1c) * ldb + o1;
  u16* Al0 = &As[w * 512];
  u16* Al1 = &As[w * 512 + 2048];
  u16* Bl0 = &Bs[w * 512];
  u16* Bl1 = &Bs[w * 512 + 2048];

  for (int k0 = ks; k0 < ke; k0 += 64) {
    gld_lds16(Ag0 + k0, Al0);
    gld_lds16(Ag1 + k0, Al1);
    gld_lds16(Bg0 + k0, Bl0);
    gld_lds16(Bg1 + k0, Bl1);
    gld_lds16(Ag0 + k0 + 32, Al0 + 4096);
    gld_lds16(Ag1 + k0 + 32, Al1 + 4096);
    gld_lds16(Bg0 + k0 + 32, Bl0 + 4096);
    gld_lds16(Bg1 + k0 + 32, Bl1 + 4096);
    __syncthreads();

#pragma unroll
    for (int s = 0; s < 2; ++s) {
      v8s af[4], bfr[4];
#pragma unroll
      for (int mi = 0; mi < 4; ++mi)
        af[mi] = *(const v8s*)&As[s * 4096 + (wr * 64 + mi * 16 + lm) * 32 + lqs];
#pragma unroll
      for (int ni = 0; ni < 4; ++ni)
        bfr[ni] = *(const v8s*)&Bs[s * 4096 + (wc * 64 + ni * 16 + lm) * 32 + lqs];
#pragma unroll
      for (int mi = 0; mi < 4; ++mi)
#pragma unroll
        for (int ni = 0; ni < 4; ++ni)
          acc[mi][ni] = __builtin_amdgcn_mfma_f32_16x16x32_bf16(af[mi], bfr[ni], acc[mi][ni], 0, 0, 0);
    }
    __syncthreads();
  }

#pragma unroll
  for (int mi = 0; mi < 4; ++mi) {
#pragma unroll
    for (int ni = 0; ni < 4; ++ni) {
      const int cc = j0 + wc * 64 + ni * 16 + lm;
      const float badd = ADDB ? bias[cc] : 0.f;
#pragma unroll
      for (int r = 0; r < 4; ++r) {
        const int rr = i0 + wr * 64 + mi * 16 + lq * 4 + r;
        float v = acc[mi][ni][r] * scale + badd;
        if (OUTBF)           ((u16*)Cv)[(size_t)rr * ldc + cc] = f2bf(v);
        else if (MODE == 2)  atomicAdd((float*)Cv + (size_t)rr * ldc + cc, v);
        else                 ((float*)Cv)[(size_t)rr * ldc + cc] = v;
      }
    }
  }
}

// ---------- 256x256 8-phase GEMM (m201 template, plain HIP) ----------
// C[M,N] = A[M,K]*B[N,K]^T, bf16 in/out, fp32 acc. 512 thr = 8 waves (2Mx4N),
// per-wave 128x64 output, BK=64, double-buffered LDS 128 KiB, K % 128 == 0.
// Per K-tile: 4 quadrant phases; 1 half-tile (2 x global_load_lds 16B) staged
// per phase; counted s_waitcnt vmcnt(6) ONLY at phases 4/8 (3 half-tiles in
// flight, 3 phases of landing slack). Raw s_barrier (no vmcnt drain).
// LDS swizzle: row of 64 elems = 8 chunks of 16B; logical chunk c stored at
// physical (c + row) & 7 -> every 8-lane ds_read_b128 group hits 8 distinct
// 16B bank slots (conflict-free). global_load_lds writes linearly, so the
// GLOBAL source is pre-rotated (both-sides rule): lane fetches logical chunk
// ((l&7) - (l>>3)) & 7 of its row.
// Stage legality (race-checked): each stage issues only after the barrier
// following its LDS region's last read:
//   P1 reads buf0.A[m0]+buf0.B(all) | stages buf1.A1 (read prev P7)
//   P2 -                            | stages buf0.B0 (read P1)
//   P3 reads buf0.A[m1]             | stages buf0.B1 (read P1)
//   P4 -                 vmcnt(6)   | stages buf0.A0 (read P1,P3)
//   P5 reads buf1.A[m0]+buf1.B(all) | stages buf0.A1 (read P1,P3)
//   P6 -                            | stages buf1.B0 (read P5)
//   P7 reads buf1.A[m1]             | stages buf1.B1 (read P5)
//   P8 -                 vmcnt(6)   | stages buf1.A0 (read P5,P7)

#define BAR()   asm volatile("s_barrier" ::: "memory")
#define LGKM0() asm volatile("s_waitcnt lgkmcnt(0)" ::: "memory")
#define VMC6()  asm volatile("s_waitcnt vmcnt(6)" ::: "memory")

#define LDA(BUF, MH) do { _Pragma("unroll") \
  for (int fi = 0; fi < 4; ++fi) { \
    const u16* ap = &As[BUF][wr][(MH) * 4096 + fi * 1024]; \
    af[fi][0] = *(const v8s*)(ap + off0); \
    af[fi][1] = *(const v8s*)(ap + off1); \
  } } while (0)

#define LDB(BUF) do { _Pragma("unroll") \
  for (int ni = 0; ni < 4; ++ni) { \
    const u16* bp = &Bs[BUF][bh][bo + ni * 1024]; \
    bfr[ni][0] = *(const v8s*)(bp + off0); \
    bfr[ni][1] = *(const v8s*)(bp + off1); \
  } } while (0)

#define MMA(MH, NL) do { _Pragma("unroll") \
  for (int fi = 0; fi < 4; ++fi) { _Pragma("unroll") \
    for (int nn = 0; nn < 2; ++nn) { \
      acc[(MH)*4+fi][(NL)+nn] = __builtin_amdgcn_mfma_f32_16x16x32_bf16( \
          af[fi][0], bfr[(NL)+nn][0], acc[(MH)*4+fi][(NL)+nn], 0, 0, 0); \
      acc[(MH)*4+fi][(NL)+nn] = __builtin_amdgcn_mfma_f32_16x16x32_bf16( \
          af[fi][1], bfr[(NL)+nn][1], acc[(MH)*4+fi][(NL)+nn], 0, 0, 0); \
    } } } while (0)

#define STG_A(BUF, H, KO) do { \
  gld_lds16(Ag + (size_t)(H) * 128 * lda + (KO), &As[BUF][H][w * 1024]); \
  gld_lds16(Ag + ((size_t)(H) * 128 + 8) * lda + (KO), &As[BUF][H][w * 1024 + 512]); \
  } while (0)

#define STG_B(BUF, H, KO) do { \
  gld_lds16(Bg + (size_t)(H) * 128 * ldb + (KO), &Bs[BUF][H][w * 1024]); \
  gld_lds16(Bg + ((size_t)(H) * 128 + 8) * ldb + (KO), &Bs[BUF][H][w * 1024 + 512]); \
  } while (0)

template<int ADDB>
__global__ __launch_bounds__(512, 2) void gemm256(
    const u16* __restrict__ A, int lda,
    const u16* __restrict__ B, int ldb,
    u16* __restrict__ C, int ldc,
    int K, const float* __restrict__ bias, float scale) {
  const int i0 = blockIdx.y * 256, j0 = blockIdx.x * 256;

  __shared__ u16 As[2][2][8192];  // [buf][half][128*64], 64 KiB
  __shared__ u16 Bs[2][2][8192];  // 64 KiB

  const int t = threadIdx.x;
  const int w = t >> 6, l = t & 63;
  const int wr = w >> 2, wc = w & 3;
  const int lm = l & 15, lq = l >> 4;
  const int bh = wc >> 1, bo = (wc & 1) * 4096;

  // fragment-read offsets within a half: row base + lm rows, physical chunk
  // (s*4 + lq + row) & 7 == (s*4 + lq + lm) & 7 (row bases are 16-aligned)
  const int off0 = lm * 64 + ((lq + lm) & 7) * 8;        // s=0
  const int off1 = lm * 64 + ((lq + lm + 4) & 7) * 8;    // s=1

  // staging: thread covers physical chunks p = (w*2+q)*64 + l, q=0,1
  // row = (w*2+q)*8 + (l>>3); logical col chunk = ((l&7) - (l>>3)) & 7
  const int srow = w * 16 + (l >> 3);
  const int scol = (((l & 7) - (l >> 3)) & 7) * 8;
  const u16* Ag = A + (size_t)(i0 + srow) * lda + scol;
  const u16* Bg = B + (size_t)(j0 + srow) * ldb + scol;

  v4f acc[8][4];
#pragma unroll
  for (int a = 0; a < 8; ++a)
#pragma unroll
    for (int b = 0; b < 4; ++b)
      acc[a][b] = v4f{0.f, 0.f, 0.f, 0.f};

  v8s af[4][2], bfr[4][2];

  // prologue: tile0 -> buf0 (B0,B1,A0,A1), tile1 -> buf1 (B0,B1,A0).
  // 14 loads issued; vmcnt(6) -> oldest 8 (all of buf0) landed.
  STG_B(0, 0, 0); STG_B(0, 1, 0); STG_A(0, 0, 0); STG_A(0, 1, 0);
  STG_B(1, 0, 64); STG_B(1, 1, 64); STG_A(1, 0, 64);
  VMC6(); BAR();

  const int nit = K >> 7;  // K % 128 == 0, >= 128
  for (int it = 0; it < nit; ++it) {
    const int kc = it << 7;
    const int k1 = kc + 64;                     // tile 2it+1 (always valid)
    int k2 = kc + 128; if (k2 >= K) k2 = 0;     // tile 2it+2 (clamped, unread)
    int k3 = kc + 192; if (k3 >= K) k3 = 0;     // tile 2it+3 (clamped, unread)

    // P1: Q(m0, n0..1) on buf0
    LDA(0, 0); LDB(0);
    STG_A(1, 1, k1);
    BAR(); LGKM0();
    __builtin_amdgcn_s_setprio(1); MMA(0, 0); __builtin_amdgcn_s_setprio(0);
    BAR();
    // P2: Q(m0, n2..3)
    STG_B(0, 0, k2);
    BAR();
    __builtin_amdgcn_s_setprio(1); MMA(0, 2); __builtin_amdgcn_s_setprio(0);
    BAR();
    // P3: Q(m1, n0..1)
    LDA(0, 1);
    STG_B(0, 1, k2);
    BAR(); LGKM0();
    __builtin_amdgcn_s_setprio(1); MMA(1, 0); __builtin_amdgcn_s_setprio(0);
    BAR();
    // P4: Q(m1, n2..3); counted wait -> buf1 fully landed before P5
    STG_A(0, 0, k2);
    BAR();
    __builtin_amdgcn_s_setprio(1); MMA(1, 2); __builtin_amdgcn_s_setprio(0);
    VMC6(); BAR();
    // P5: Q(m0, n0..1) on buf1
    LDA(1, 0); LDB(1);
    STG_A(0, 1, k2);
    BAR(); LGKM0();
    __builtin_amdgcn_s_setprio(1); MMA(0, 0); __builtin_amdgcn_s_setprio(0);
    BAR();
    // P6: Q(m0, n2..3)
    STG_B(1, 0, k3);
    BAR();
    __builtin_amdgcn_s_setprio(1); MMA(0, 2); __builtin_amdgcn_s_setprio(0);
    BAR();
    // P7: Q(m1, n0..1)
    LDA(1, 1);
    STG_B(1, 1, k3);
    BAR(); LGKM0();
    __builtin_amdgcn_s_setprio(1); MMA(1, 0); __builtin_amdgcn_s_setprio(0);
    BAR();
    // P8: Q(m1, n2..3); counted wait -> buf0 fully landed before next P1
    STG_A(1, 0, k3);
    BAR();
    __builtin_amdgcn_s_setprio(1); MMA(1, 2); __builtin_amdgcn_s_setprio(0);
    VMC6(); BAR();
  }

  // epilogue: C/D layout col=lane&15, row=quad*4+reg [m89-verified]
#pragma unroll
  for (int mi = 0; mi < 8; ++mi) {
#pragma unroll
    for (int ni = 0; ni < 4; ++ni) {
      const int cc = j0 + wc * 64 + ni * 16 + lm;
      const float badd = ADDB ? bias[cc] : 0.f;
#pragma unroll
      for (int r = 0; r < 4; ++r) {
        const int rr = i0 + wr * 128 + mi * 16 + lq * 4 + r;
        C[(size_t)rr * ldc + cc] = f2bf(acc[mi][ni][r] * scale + badd);
      }
    }
  }
}

#undef LDA
#undef LDB
#undef MMA
#undef STG_A
#undef STG_B

// ---------- row softmax with causal + padding mask (single bf16 input) ----------
__global__ __launch_bounds__(256) void softmax_rows(
    const u16* __restrict__ S0,
    u16* __restrict__ att, const int* __restrict__ npad_p) {
  const int i = blockIdx.x;
  const int np = *npad_p;
  const int kend = ((i >> 7) + 1) << 7;
  const u16* r0 = S0 + (size_t)i * SEQ;
  u16* arow = att + (size_t)i * SEQ;
  const int t = threadIdx.x;

  float m = -3.0e38f, s = 0.f;
  for (int j = np + t; j <= i; j += 256) {
    float v = bf2f(r0[j]);
    if (v > m) { s = s * __expf(m - v) + 1.f; m = v; }
    else       { s += __expf(v - m); }
  }
#pragma unroll
  for (int off = 32; off > 0; off >>= 1) {
    float mo = __shfl_xor(m, off);
    float so = __shfl_xor(s, off);
    float M = fmaxf(m, mo);
    s = s * __expf(m - M) + so * __expf(mo - M);
    m = M;
  }
  __shared__ float sm[4], ss[4];
  const int w = t >> 6, l = t & 63;
  if (l == 0) { sm[w] = m; ss[w] = s; }
  __syncthreads();
  const float M = fmaxf(fmaxf(sm[0], sm[1]), fmaxf(sm[2], sm[3]));
  const float Ssum = ss[0] * __expf(sm[0] - M) + ss[1] * __expf(sm[1] - M) +
                     ss[2] * __expf(sm[2] - M) + ss[3] * __expf(sm[3] - M);
  const float inv = 1.f / Ssum;  // padded rows masked to 0 below; inv unused there

  for (int j0b = t * 8; j0b < kend; j0b += 2048) {
    union { u16 s8[8]; uint4 v; } u;
#pragma unroll
    for (int q = 0; q < 8; ++q) {
      const int j = j0b + q;
      float a = 0.f;
      if (j >= np && j <= i)
        a = __expf(bf2f(r0[j]) - M) * inv;
      u.s8[q] = f2bf(a);
    }
    *(uint4*)(arow + j0b) = u.v;
  }
}

// ---------- launch ----------

extern "C" void kernel_launch(void* const* d_in, const int* in_sizes, int n_in,
                              void* d_out, int out_size, void* d_ws, size_t ws_size,
                              hipStream_t stream) {
  const float* x = (const float*)d_in[0];
  const float* W = (const float*)d_in[1];
  const float* b = (const float*)d_in[2];
  const int* npad = (const int*)d_in[3];
  float* out = (float*)d_out;

  // workspace:
  // [xb 16MB | Wt 24MB] reused as att 32MB ][ qkvb 48MB ][ vt 16MB ][ sc0 32MB ]
  char* p = (char*)d_ws;
  u16* xb = (u16*)p;
  u16* Wt = (u16*)(p + (size_t)SEQ * FEAT * 2);
  u16* att = (u16*)p;
  p += (size_t)SEQ * FEAT * 2 + (size_t)F3 * FEAT * 2;
  u16* qkvb = (u16*)p;  p += (size_t)SEQ * F3 * 2;
  u16* vt   = (u16*)p;  p += (size_t)FEAT * SEQ * 2;
  u16* sc0  = (u16*)p;  p += (size_t)SEQ * SEQ * 2;   // bf16 scores (full rows)
  if (ws_size < (size_t)(p - (char*)d_ws)) return;

  const float scale = 0.02209708691207961f;  // 1/sqrt(2048)

  // zero d_out (att@v split-K atomically accumulates into it)
  hipMemsetAsync(d_out, 0, (size_t)SEQ * FEAT * sizeof(float), stream);

  cvt_f32_bf16<<<SEQ * FEAT / 8 / 256, 256, 0, stream>>>(x, xb, SEQ * FEAT / 8);
  transp_f2b<<<dim3(F3 / 32, FEAT / 32), dim3(32, 8), 0, stream>>>(W, F3, Wt, FEAT);
  // qkv = x @ W + b (bf16): 8-phase 256^2, 24x16 = 384 blocks
  gemm256<1><<<dim3(F3 / 256, SEQ / 256), 512, 0, stream>>>(
      xb, FEAT, Wt, FEAT, qkvb, F3, FEAT, b, 1.0f);
  transp_b2b<<<dim3(FEAT / 32, SEQ / 32), dim3(32, 8), 0, stream>>>(
      qkvb + 2 * FEAT, F3, vt, SEQ);
  // scores = (q @ k^T)/sqrt(F): full 16x16 grid (256 blocks = 1/CU), no split-K
  gemm256<0><<<dim3(SEQ / 256, SEQ / 256), 512, 0, stream>>>(
      qkvb, F3, qkvb + FEAT, F3, sc0, SEQ, FEAT, nullptr, scale);
  softmax_rows<<<SEQ, 256, 0, stream>>>(sc0, att, npad);
  // out = att @ v: causal split-K=2, atomic fp32 (proven 128^2 kernel)
  gemm_bt<0, 0, 2><<<dim3(FEAT / 128, SEQ / 128, 2), 256, 0, stream>>>(
      att, SEQ, vt, SEQ, (void*)out, FEAT, 0, nullptr, 1.0f);
}